// Round 1
// baseline (308.844 us; speedup 1.0000x reference)
//
#include <hip/hip_runtime.h>

// ---------------------------------------------------------------------------
// BasicAttention: dwconv3x3 -> pointwise 1x1 (C->3C) -> 4-head attention S=4096
// B=4, C=256, H=W=64, heads=4, d=64. Output f32 [B,C,H,W].
//
// Pipeline:
//  k_wcvt : w_pw f32 -> bf16, 0.125*log2e folded into q rows
//  k_dw   : depthwise conv -> DWt[b][s][c] bf16 (c-contiguous, via LDS transpose)
//  k_pw   : GEMM qkv[o,s] = W[o,c] x DWt[s,c]^T, MFMA 16x16x32 bf16
//           -> Q[b,h,s,d], K[b,h,s,d], Vt[b,h,d,s] bf16
//  k_attn : flash attention, 64-row q tiles, 64-col kv tiles, online softmax
// ---------------------------------------------------------------------------

typedef __attribute__((ext_vector_type(8))) __bf16 bf16x8;
typedef __attribute__((ext_vector_type(4))) float f32x4;
typedef __attribute__((ext_vector_type(8))) unsigned short ushort8;

#define OFF_DW 0ull
#define OFF_WB 8388608ull
#define OFF_Q  8781824ull
#define OFF_K  17170432ull
#define OFF_V  25559040ull
// total ws use: ~32.4 MB

__device__ __forceinline__ unsigned short f2bf(float x) {
  unsigned u = __builtin_bit_cast(unsigned, x);
  u += 0x7fffu + ((u >> 16) & 1u);           // RNE
  return (unsigned short)(u >> 16);
}

__device__ __forceinline__ void gld16(const void* g, void* l) {
  // async global->LDS, 16B/lane; LDS dest = uniform base + lane*16 (linear)
  __builtin_amdgcn_global_load_lds((const __attribute__((address_space(1))) void*)g,
                                   (__attribute__((address_space(3))) void*)l, 16, 0, 0);
}

// ---------------- kernel 0: convert w_pw to bf16, fold softmax scale --------
__global__ __launch_bounds__(256) void k_wcvt(const float* __restrict__ wpw,
                                              unsigned short* __restrict__ wbf) {
  int idx = blockIdx.x * 256 + threadIdx.x;       // 768*256 total
  int o = idx >> 8;
  float v = wpw[idx];
  if (o < 256) v *= 0.18033688011112042f;         // 0.125 * log2(e) -> exp2 softmax
  wbf[idx] = f2bf(v);
}

// ---------------- kernel 1: depthwise 3x3 conv -> DWt[b][s][c] bf16 ---------
__global__ __launch_bounds__(256) void k_dw(const float* __restrict__ x,
                                            const float* __restrict__ wdw,
                                            unsigned short* __restrict__ dwt) {
  __shared__ float tile[64 * 65];                 // [s=w][c], 65 stride: conflict-free
  const int t = threadIdx.x;
  const int h = blockIdx.x;                       // s-tile == one image row
  const int c0 = blockIdx.y * 64;
  const int b = blockIdx.z;
  const int w = t & 63;
  const int wq = t >> 6;
#pragma unroll
  for (int i = 0; i < 16; ++i) {
    int cl = wq * 16 + i;
    int c = c0 + cl;
    const float* wd = wdw + c * 9;
    const float* xb = x + ((size_t)(b * 256 + c) * 64) * 64;
    float acc = 0.f;
#pragma unroll
    for (int ky = 0; ky < 3; ++ky) {
      int hh = h + ky - 1;
      if ((unsigned)hh < 64u) {
        const float* row = xb + hh * 64;
#pragma unroll
        for (int kx = 0; kx < 3; ++kx) {
          int ww = w + kx - 1;
          if ((unsigned)ww < 64u) acc += row[ww] * wd[ky * 3 + kx];
        }
      }
    }
    tile[w * 65 + cl] = acc;
  }
  __syncthreads();
  int sl = t >> 2, cch = (t & 3) * 16;
  ushort8 p0, p1;
#pragma unroll
  for (int j = 0; j < 8; ++j) p0[j] = f2bf(tile[sl * 65 + cch + j]);
#pragma unroll
  for (int j = 0; j < 8; ++j) p1[j] = f2bf(tile[sl * 65 + cch + 8 + j]);
  unsigned short* dst = dwt + ((size_t)(b * 4096 + h * 64 + sl)) * 256 + c0 + cch;
  *(ushort8*)dst = p0;
  *(ushort8*)(dst + 8) = p1;
}

// ---------------- kernel 2: pointwise GEMM -> Q,K,Vt ------------------------
__global__ __launch_bounds__(256) void k_pw(const unsigned short* __restrict__ dwt,
                                            const unsigned short* __restrict__ wbf,
                                            unsigned short* __restrict__ q,
                                            unsigned short* __restrict__ k,
                                            unsigned short* __restrict__ v) {
  __shared__ __align__(16) unsigned char smem[65536];   // W 32KB | DW 32KB
  const int t = threadIdx.x;
  const int lane = t & 63, wv = t >> 6;
  const int s0 = blockIdx.x * 64;
  const int yy = blockIdx.y;                            // o-tile 0..11
  const int b = blockIdx.z;
  // staging: rows are 512B (32 chunks); LDS[row][slot] = G[row][slot ^ (row&7)]
  const int vb = ((lane >> 5) << 9) + (((lane & 31) ^ (lane >> 5)) << 4);
  const char* wsrc = (const char*)wbf + (size_t)yy * 32768;
  const char* dsrc = (const char*)dwt + ((size_t)(b * 4096 + s0)) * 512;
#pragma unroll
  for (int i = 0; i < 8; ++i) {
    int I = wv * 8 + i;
    int u = ((2 * i) & 7) << 4;                         // (2I)&7 == (2i)&7
    gld16(wsrc + (size_t)I * 1024 + (vb ^ u), smem + I * 1024);
    gld16(dsrc + (size_t)I * 1024 + (vb ^ u), smem + 32768 + I * 1024);
  }
  asm volatile("s_waitcnt vmcnt(0)" ::: "memory");
  __syncthreads();

  const int c15 = lane & 15, g = lane >> 4;
  f32x4 acc[4] = {{0,0,0,0},{0,0,0,0},{0,0,0,0},{0,0,0,0}};
  const int orow = wv * 16 + c15;
#pragma unroll
  for (int kc = 0; kc < 8; ++kc) {
    bf16x8 a = *(const bf16x8*)(smem + orow * 512 + (((kc * 4 + g) ^ (orow & 7)) << 4));
#pragma unroll
    for (int nt = 0; nt < 4; ++nt) {
      int srow = nt * 16 + c15;
      bf16x8 bb = *(const bf16x8*)(smem + 32768 + srow * 512 + (((kc * 4 + g) ^ (srow & 7)) << 4));
      acc[nt] = __builtin_amdgcn_mfma_f32_16x16x32_bf16(a, bb, acc[nt], 0, 0, 0);
    }
  }
  __syncthreads();

  const int type = yy >> 2, head = yy & 3;
  const size_t bh = (size_t)(b * 4 + head);
  if (type == 2) {
    // V: natural [d][s] layout, direct scatter
#pragma unroll
    for (int nt = 0; nt < 4; ++nt)
#pragma unroll
      for (int r = 0; r < 4; ++r) {
        int d = wv * 16 + g * 4 + r;
        int sg = s0 + nt * 16 + c15;
        v[(bh * 64 + d) * 4096 + sg] = f2bf(acc[nt][r]);
      }
  } else {
    // Q/K need [s][d]: transpose via LDS bounce (reuse W region)
    float* ol = (float*)smem;
#pragma unroll
    for (int nt = 0; nt < 4; ++nt)
#pragma unroll
      for (int r = 0; r < 4; ++r)
        ol[(nt * 16 + c15) * 65 + (wv * 16 + g * 4 + r)] = acc[nt][r];
    __syncthreads();
    unsigned short* dst0 = (type == 0) ? q : k;
    int sl = t >> 2, dch = (t & 3) * 16;
    ushort8 p0, p1;
#pragma unroll
    for (int j = 0; j < 8; ++j) p0[j] = f2bf(ol[sl * 65 + dch + j]);
#pragma unroll
    for (int j = 0; j < 8; ++j) p1[j] = f2bf(ol[sl * 65 + dch + 8 + j]);
    unsigned short* dst = dst0 + (bh * 4096 + s0 + sl) * 64 + dch;
    *(ushort8*)dst = p0;
    *(ushort8*)(dst + 8) = p1;
  }
}

// ---------------- kernel 3: flash attention ---------------------------------
__global__ __launch_bounds__(256) void k_attn(const unsigned short* __restrict__ qg,
                                              const unsigned short* __restrict__ kg,
                                              const unsigned short* __restrict__ vg,
                                              float* __restrict__ out) {
  __shared__ __align__(16) unsigned char smem[32768];   // Q 8K | K 8K | V 8K | P 4x2K
  const int t = threadIdx.x;
  const int lane = t & 63, wv = t >> 6;
  const int c15 = lane & 15, g = lane >> 4;
  const int s0 = blockIdx.x * 64;
  const int head = blockIdx.y, b = blockIdx.z;
  const size_t bh = (size_t)(b * 4 + head);
  const char* qsrc = (const char*)qg + bh * 524288 + (size_t)s0 * 128;
  const char* ksrc = (const char*)kg + bh * 524288;
  const char* vsrc = (const char*)vg + bh * 524288;
  // per-lane staging offsets; rows 128B (8 chunks), slot = chunk ^ (row&7)
  const int vQK = ((lane >> 3) << 7) + ((((lane & 7) ^ (lane >> 3))) << 4);
  const int vV  = ((lane >> 3) << 13) + ((((lane & 7) ^ (lane >> 3))) << 4);

  {                                                     // stage Q once
    int I0 = wv * 2;
    gld16(qsrc + (size_t)I0 * 1024 + vQK, smem + I0 * 1024);
    gld16(qsrc + (size_t)(I0 + 1) * 1024 + vQK, smem + (I0 + 1) * 1024);
  }
  asm volatile("s_waitcnt vmcnt(0)" ::: "memory");
  __syncthreads();
  bf16x8 aq0 = *(const bf16x8*)(smem + (wv * 16 + c15) * 128 + (((0 + g) ^ (c15 & 7)) << 4));
  bf16x8 aq1 = *(const bf16x8*)(smem + (wv * 16 + c15) * 128 + (((4 + g) ^ (c15 & 7)) << 4));

  f32x4 oacc[4] = {{0,0,0,0},{0,0,0,0},{0,0,0,0},{0,0,0,0}};
  float mrow[4] = {-3e38f, -3e38f, -3e38f, -3e38f};
  float lrow[4] = {0.f, 0.f, 0.f, 0.f};

#pragma unroll 1
  for (int it = 0; it < 64; ++it) {
    __syncthreads();                                    // prev iter LDS reads done
    {
      int I0 = wv * 2;
      gld16(ksrc + (size_t)it * 8192 + (size_t)I0 * 1024 + vQK, smem + 8192 + I0 * 1024);
      gld16(ksrc + (size_t)it * 8192 + (size_t)(I0 + 1) * 1024 + vQK, smem + 8192 + (I0 + 1) * 1024);
      gld16(vsrc + (size_t)it * 128 + (size_t)I0 * 65536 + vV, smem + 16384 + I0 * 1024);
      gld16(vsrc + (size_t)it * 128 + (size_t)(I0 + 1) * 65536 + vV, smem + 16384 + (I0 + 1) * 1024);
    }
    asm volatile("s_waitcnt vmcnt(0)" ::: "memory");
    __syncthreads();

    // QK^T: D[s(rows), t(cols)]
    f32x4 sc[4] = {{0,0,0,0},{0,0,0,0},{0,0,0,0},{0,0,0,0}};
#pragma unroll
    for (int nt = 0; nt < 4; ++nt) {
      int trow = nt * 16 + c15;
      bf16x8 b0 = *(const bf16x8*)(smem + 8192 + trow * 128 + (((0 + g) ^ (c15 & 7)) << 4));
      sc[nt] = __builtin_amdgcn_mfma_f32_16x16x32_bf16(aq0, b0, sc[nt], 0, 0, 0);
      bf16x8 b1 = *(const bf16x8*)(smem + 8192 + trow * 128 + (((4 + g) ^ (c15 & 7)) << 4));
      sc[nt] = __builtin_amdgcn_mfma_f32_16x16x32_bf16(aq1, b1, sc[nt], 0, 0, 0);
    }

    // online softmax (rows live on lanes sharing g; reduce across 16 cols)
    unsigned short* pl = (unsigned short*)(smem + 24576 + wv * 2048);
#pragma unroll
    for (int r = 0; r < 4; ++r) {
      float vmx = fmaxf(fmaxf(sc[0][r], sc[1][r]), fmaxf(sc[2][r], sc[3][r]));
      vmx = fmaxf(vmx, __shfl_xor(vmx, 1));
      vmx = fmaxf(vmx, __shfl_xor(vmx, 2));
      vmx = fmaxf(vmx, __shfl_xor(vmx, 4));
      vmx = fmaxf(vmx, __shfl_xor(vmx, 8));
      float mn = fmaxf(mrow[r], vmx);
      float sf = exp2f(mrow[r] - mn);
      mrow[r] = mn;
      float rs = 0.f;
#pragma unroll
      for (int nt = 0; nt < 4; ++nt) {
        float p = exp2f(sc[nt][r] - mn);
        sc[nt][r] = p;
        rs += p;
      }
      rs += __shfl_xor(rs, 1);
      rs += __shfl_xor(rs, 2);
      rs += __shfl_xor(rs, 4);
      rs += __shfl_xor(rs, 8);
      lrow[r] = lrow[r] * sf + rs;
      oacc[0][r] *= sf; oacc[1][r] *= sf; oacc[2][r] *= sf; oacc[3][r] *= sf;
    }
    // P -> per-wave LDS (bf16, swizzled)
#pragma unroll
    for (int r = 0; r < 4; ++r) {
      int row = g * 4 + r, rs7 = row & 7;
#pragma unroll
      for (int nt = 0; nt < 4; ++nt) {
        int tc = nt * 16 + c15;
        pl[row * 64 + (((tc >> 3) ^ rs7) << 3) + (tc & 7)] = f2bf(sc[nt][r]);
      }
    }
    __syncthreads();
    bf16x8 ap0 = *(const bf16x8*)((unsigned char*)pl + c15 * 128 + (((0 + g) ^ (c15 & 7)) << 4));
    bf16x8 ap1 = *(const bf16x8*)((unsigned char*)pl + c15 * 128 + (((4 + g) ^ (c15 & 7)) << 4));
#pragma unroll
    for (int dt = 0; dt < 4; ++dt) {
      int drow = dt * 16 + c15;
      bf16x8 bv0 = *(const bf16x8*)(smem + 16384 + drow * 128 + (((0 + g) ^ (c15 & 7)) << 4));
      oacc[dt] = __builtin_amdgcn_mfma_f32_16x16x32_bf16(ap0, bv0, oacc[dt], 0, 0, 0);
      bf16x8 bv1 = *(const bf16x8*)(smem + 16384 + drow * 128 + (((4 + g) ^ (c15 & 7)) << 4));
      oacc[dt] = __builtin_amdgcn_mfma_f32_16x16x32_bf16(ap1, bv1, oacc[dt], 0, 0, 0);
    }
  }

  // epilogue: normalize, transpose [s][d] -> [d][s] via LDS, coalesced f32 out
  float inv[4];
#pragma unroll
  for (int r = 0; r < 4; ++r) inv[r] = 1.f / lrow[r];
  __syncthreads();
  float* ol = (float*)smem;
#pragma unroll
  for (int dt = 0; dt < 4; ++dt)
#pragma unroll
    for (int r = 0; r < 4; ++r)
      ol[(dt * 16 + c15) * 65 + (wv * 16 + g * 4 + r)] = oacc[dt][r] * inv[r];
  __syncthreads();
  int drow = t >> 2, sch = (t & 3) * 16;
  float* ob = out + ((size_t)(b * 256 + head * 64 + drow)) * 4096 + s0 + sch;
#pragma unroll
  for (int jj = 0; jj < 4; ++jj) {
    float4 vv = make_float4(ol[drow * 65 + sch + jj * 4 + 0], ol[drow * 65 + sch + jj * 4 + 1],
                            ol[drow * 65 + sch + jj * 4 + 2], ol[drow * 65 + sch + jj * 4 + 3]);
    ((float4*)ob)[jj] = vv;
  }
}

// ---------------------------------------------------------------------------
extern "C" void kernel_launch(void* const* d_in, const int* in_sizes, int n_in,
                              void* d_out, int out_size, void* d_ws, size_t ws_size,
                              hipStream_t stream) {
  const float* x = (const float*)d_in[0];
  const float* wdw = (const float*)d_in[1];
  const float* wpw = (const float*)d_in[2];
  float* out = (float*)d_out;
  char* ws = (char*)d_ws;
  unsigned short* dwt = (unsigned short*)(ws + OFF_DW);
  unsigned short* wbf = (unsigned short*)(ws + OFF_WB);
  unsigned short* q = (unsigned short*)(ws + OFF_Q);
  unsigned short* k = (unsigned short*)(ws + OFF_K);
  unsigned short* v = (unsigned short*)(ws + OFF_V);

  k_wcvt<<<dim3(768), dim3(256), 0, stream>>>(wpw, wbf);
  k_dw<<<dim3(64, 4, 4), dim3(256), 0, stream>>>(x, wdw, dwt);
  k_pw<<<dim3(64, 12, 4), dim3(256), 0, stream>>>(dwt, wbf, q, k, v);
  k_attn<<<dim3(64, 4, 4), dim3(256), 0, stream>>>(q, k, v, out);
}

// Round 5
// 158.444 us; speedup vs baseline: 1.9492x; 1.9492x over previous
//
#include <hip/hip_runtime.h>

// ---------------------------------------------------------------------------
// BasicAttention: dwconv3x3 -> pointwise 1x1 (C->3C) -> 4-head attention S=4096
// B=4, C=256, H=W=64, heads=4, d=64. Output f32 [B,C,H,W].
//
//  k_wcvt : w_pw f32 -> bf16, 0.125*log2e folded into q rows
//  k_dw   : depthwise conv -> DWt[b][s][c] bf16 (c-contiguous, via LDS transpose)
//  k_pw   : GEMM -> Q[b,h,s,d], K[b,h,s,d], Vt[b,h,d,s] bf16
//  k_attn : flash attention, swapped QK^T (S^T=mfma(K,Q)) -> in-register
//           softmax, defer-max (T13), l via ones-MFMA, K/V dbuf
//           global_load_lds (T14), 8 waves x 32 q-rows.
//
// Round-5 note: all cross-half exchanges now use __shfl_xor(...,32) (HIP-
// guaranteed semantics). v_permlane32_swap_b32 was abandoned after rounds
// 2-4 produced mutually contradictory evidence about its row-pairing
// convention / register-allocation interaction.
// ---------------------------------------------------------------------------

typedef __attribute__((ext_vector_type(8))) __bf16 bf16x8;
typedef __attribute__((ext_vector_type(4))) float f32x4;
typedef __attribute__((ext_vector_type(16))) float f32x16;
typedef __attribute__((ext_vector_type(8))) unsigned short ushort8;
typedef __attribute__((ext_vector_type(4))) unsigned int uint4v;

#define OFF_DW 0ull
#define OFF_WB 8388608ull
#define OFF_Q  8781824ull
#define OFF_K  17170432ull
#define OFF_V  25559040ull

__device__ __forceinline__ unsigned short f2bf(float x) {
  unsigned u = __builtin_bit_cast(unsigned, x);
  u += 0x7fffu + ((u >> 16) & 1u);           // RNE
  return (unsigned short)(u >> 16);
}

__device__ __forceinline__ void gld16(const void* g, void* l) {
  __builtin_amdgcn_global_load_lds((const __attribute__((address_space(1))) void*)g,
                                   (__attribute__((address_space(3))) void*)l, 16, 0, 0);
}

__device__ __forceinline__ unsigned cvtpk(float lo, float hi) {
  unsigned r;
  asm("v_cvt_pk_bf16_f32 %0, %1, %2" : "=v"(r) : "v"(lo), "v"(hi));
  return r;
}

// ---------------- kernel 0: convert w_pw to bf16, fold softmax scale --------
__global__ __launch_bounds__(256) void k_wcvt(const float* __restrict__ wpw,
                                              unsigned short* __restrict__ wbf) {
  int idx = blockIdx.x * 256 + threadIdx.x;
  int o = idx >> 8;
  float v = wpw[idx];
  if (o < 256) v *= 0.18033688011112042f;         // 0.125 * log2(e)
  wbf[idx] = f2bf(v);
}

// ---------------- kernel 1: depthwise 3x3 conv -> DWt[b][s][c] bf16 ---------
__global__ __launch_bounds__(256) void k_dw(const float* __restrict__ x,
                                            const float* __restrict__ wdw,
                                            unsigned short* __restrict__ dwt) {
  __shared__ float tile[64 * 65];
  const int t = threadIdx.x;
  const int h = blockIdx.x;
  const int c0 = blockIdx.y * 64;
  const int b = blockIdx.z;
  const int w = t & 63;
  const int wq = t >> 6;
#pragma unroll
  for (int i = 0; i < 16; ++i) {
    int cl = wq * 16 + i;
    int c = c0 + cl;
    const float* wd = wdw + c * 9;
    const float* xb = x + ((size_t)(b * 256 + c) * 64) * 64;
    float acc = 0.f;
#pragma unroll
    for (int ky = 0; ky < 3; ++ky) {
      int hh = h + ky - 1;
      if ((unsigned)hh < 64u) {
        const float* row = xb + hh * 64;
#pragma unroll
        for (int kx = 0; kx < 3; ++kx) {
          int ww = w + kx - 1;
          if ((unsigned)ww < 64u) acc += row[ww] * wd[ky * 3 + kx];
        }
      }
    }
    tile[w * 65 + cl] = acc;
  }
  __syncthreads();
  int sl = t >> 2, cch = (t & 3) * 16;
  ushort8 p0, p1;
#pragma unroll
  for (int j = 0; j < 8; ++j) p0[j] = f2bf(tile[sl * 65 + cch + j]);
#pragma unroll
  for (int j = 0; j < 8; ++j) p1[j] = f2bf(tile[sl * 65 + cch + 8 + j]);
  unsigned short* dst = dwt + ((size_t)(b * 4096 + h * 64 + sl)) * 256 + c0 + cch;
  *(ushort8*)dst = p0;
  *(ushort8*)(dst + 8) = p1;
}

// ---------------- kernel 2: pointwise GEMM -> Q,K,Vt ------------------------
__global__ __launch_bounds__(256) void k_pw(const unsigned short* __restrict__ dwt,
                                            const unsigned short* __restrict__ wbf,
                                            unsigned short* __restrict__ q,
                                            unsigned short* __restrict__ k,
                                            unsigned short* __restrict__ v) {
  __shared__ __align__(16) unsigned char smem[65536];
  const int t = threadIdx.x;
  const int lane = t & 63, wv = t >> 6;
  const int s0 = blockIdx.x * 64;
  const int yy = blockIdx.y;
  const int b = blockIdx.z;
  const int vb = ((lane >> 5) << 9) + (((lane & 31) ^ (lane >> 5)) << 4);
  const char* wsrc = (const char*)wbf + (size_t)yy * 32768;
  const char* dsrc = (const char*)dwt + ((size_t)(b * 4096 + s0)) * 512;
#pragma unroll
  for (int i = 0; i < 8; ++i) {
    int I = wv * 8 + i;
    int u = ((2 * i) & 7) << 4;
    gld16(wsrc + (size_t)I * 1024 + (vb ^ u), smem + I * 1024);
    gld16(dsrc + (size_t)I * 1024 + (vb ^ u), smem + 32768 + I * 1024);
  }
  asm volatile("s_waitcnt vmcnt(0)" ::: "memory");
  __syncthreads();

  const int c15 = lane & 15, g = lane >> 4;
  f32x4 acc[4] = {{0,0,0,0},{0,0,0,0},{0,0,0,0},{0,0,0,0}};
  const int orow = wv * 16 + c15;
#pragma unroll
  for (int kc = 0; kc < 8; ++kc) {
    bf16x8 a = *(const bf16x8*)(smem + orow * 512 + (((kc * 4 + g) ^ (orow & 7)) << 4));
#pragma unroll
    for (int nt = 0; nt < 4; ++nt) {
      int srow = nt * 16 + c15;
      bf16x8 bb = *(const bf16x8*)(smem + 32768 + srow * 512 + (((kc * 4 + g) ^ (srow & 7)) << 4));
      acc[nt] = __builtin_amdgcn_mfma_f32_16x16x32_bf16(a, bb, acc[nt], 0, 0, 0);
    }
  }
  __syncthreads();

  const int type = yy >> 2, head = yy & 3;
  const size_t bh = (size_t)(b * 4 + head);
  if (type == 2) {
#pragma unroll
    for (int nt = 0; nt < 4; ++nt)
#pragma unroll
      for (int r = 0; r < 4; ++r) {
        int d = wv * 16 + g * 4 + r;
        int sg = s0 + nt * 16 + c15;
        v[(bh * 64 + d) * 4096 + sg] = f2bf(acc[nt][r]);
      }
  } else {
    float* ol = (float*)smem;
#pragma unroll
    for (int nt = 0; nt < 4; ++nt)
#pragma unroll
      for (int r = 0; r < 4; ++r)
        ol[(nt * 16 + c15) * 65 + (wv * 16 + g * 4 + r)] = acc[nt][r];
    __syncthreads();
    unsigned short* dst0 = (type == 0) ? q : k;
    int sl = t >> 2, dch = (t & 3) * 16;
    ushort8 p0, p1;
#pragma unroll
    for (int j = 0; j < 8; ++j) p0[j] = f2bf(ol[sl * 65 + dch + j]);
#pragma unroll
    for (int j = 0; j < 8; ++j) p1[j] = f2bf(ol[sl * 65 + dch + 8 + j]);
    unsigned short* dst = dst0 + (bh * 4096 + s0 + sl) * 64 + dch;
    *(ushort8*)dst = p0;
    *(ushort8*)(dst + 8) = p1;
  }
}

// ---------------- kernel 3: flash attention (swapped QK^T, in-reg softmax) --
// grid 256 = (xcd-grouped bh, stile); 8 waves x 32 q-rows; KVBLK=64 dbuf.
__global__ __launch_bounds__(512) void k_attn(const unsigned short* __restrict__ qg,
                                              const unsigned short* __restrict__ kg,
                                              const unsigned short* __restrict__ vg,
                                              float* __restrict__ out) {
  __shared__ __align__(16) unsigned char smem[65536];
  const int t = threadIdx.x;
  const int lane = t & 63, wv = t >> 6;
  const int l31 = lane & 31, hi = lane >> 5;

  const int blk = blockIdx.x;
  const int xcd = blk & 7, idx = blk >> 3;
  const int bh = xcd * 2 + (idx & 1);            // same-bh blocks share an XCD L2
  const int s0 = (idx >> 1) * 256;

  const char* qsrc = (const char*)qg + (size_t)bh * 524288 + (size_t)s0 * 128;
  const char* ksrc = (const char*)kg + (size_t)bh * 524288;
  const char* vsrc = (const char*)vg + (size_t)bh * 524288;
  // staging swizzle: 8 rows of 128B per gld16-wave; slot = chunk ^ (row&7)
  const int vQK = ((lane >> 3) << 7) + (((lane & 7) ^ (lane >> 3)) << 4);
  const int vV  = ((lane >> 3) << 13) + (((lane & 7) ^ (lane >> 3)) << 4);

  // prologue: stage Q (32KB) + K/V tile 0
#pragma unroll
  for (int i = 0; i < 4; ++i) {
    int I = wv * 4 + i;
    gld16(qsrc + (size_t)I * 1024 + vQK, smem + I * 1024);
  }
  if (wv < 4) {
#pragma unroll
    for (int i = 0; i < 2; ++i) {
      int I = wv * 2 + i;
      gld16(ksrc + (size_t)I * 1024 + vQK, smem + 32768 + I * 1024);
    }
  } else {
#pragma unroll
    for (int i = 0; i < 2; ++i) {
      int I = (wv - 4) * 2 + i;
      gld16(vsrc + (size_t)I * 65536 + vV, smem + 40960 + I * 1024);
    }
  }
  asm volatile("s_waitcnt vmcnt(0)" ::: "memory");
  __syncthreads();

  // Q fragments (B-operand: lane holds Q[s=wv*32+l31][d = 16*ks + 8*hi + j])
  bf16x8 qf[4];
  {
    int row = wv * 32 + l31;
#pragma unroll
    for (int ks = 0; ks < 4; ++ks)
      qf[ks] = *(const bf16x8*)(smem + row * 128 + (((ks * 2 + hi) ^ (row & 7)) << 4));
  }

  f32x16 O0, O1, lacc;
#pragma unroll
  for (int r = 0; r < 16; ++r) { O0[r] = 0.f; O1[r] = 0.f; lacc[r] = 0.f; }
  float m = -1e30f;
  float* sflp = (float*)(smem + wv * 4096);       // wave-private (old Q rows)

  uint4v onesu;
  onesu[0] = onesu[1] = onesu[2] = onesu[3] = 0x3F803F80u;  // bf16 1.0 x8
  const bf16x8 onesb = __builtin_bit_cast(bf16x8, onesu);

#pragma unroll 1
  for (int it = 0; it < 64; ++it) {
    const unsigned char* kb = smem + 32768 + (it & 1) * 16384;
    const unsigned char* vbuf = kb + 8192;
    unsigned char* nb = smem + 32768 + ((it + 1) & 1) * 16384;
    if (it < 63) {                                // stage next tile (2 gld16/wave)
      if (wv < 4) {
#pragma unroll
        for (int i = 0; i < 2; ++i) {
          int I = wv * 2 + i;
          gld16(ksrc + (size_t)(it + 1) * 8192 + (size_t)I * 1024 + vQK, nb + I * 1024);
        }
      } else {
#pragma unroll
        for (int i = 0; i < 2; ++i) {
          int I = (wv - 4) * 2 + i;
          gld16(vsrc + (size_t)(it + 1) * 128 + (size_t)I * 65536 + vV, nb + 8192 + I * 1024);
        }
      }
    }

    // QK^T swapped: S^T[t][s], col=lane&31 = s (q-row lane-local).
    // sc reg r holds t = (r&3) + 8*(r>>2) + 4*hi (within 32-block).
    f32x16 sc0, sc1;
#pragma unroll
    for (int r = 0; r < 16; ++r) { sc0[r] = 0.f; sc1[r] = 0.f; }
#pragma unroll
    for (int ks = 0; ks < 4; ++ks) {
      int sw = ((ks * 2 + hi) ^ (l31 & 7)) << 4;
      bf16x8 kf0 = *(const bf16x8*)(kb + l31 * 128 + sw);
      sc0 = __builtin_amdgcn_mfma_f32_32x32x16_bf16(kf0, qf[ks], sc0, 0, 0, 0);
      bf16x8 kf1 = *(const bf16x8*)(kb + (32 + l31) * 128 + sw);
      sc1 = __builtin_amdgcn_mfma_f32_32x32x16_bf16(kf1, qf[ks], sc1, 0, 0, 0);
    }

    // row max: 31 in-lane fmax + 1 cross-half shfl_xor (HIP-defined semantics)
    float pmax = fmaxf(sc0[0], sc0[1]);
#pragma unroll
    for (int r = 2; r < 16; ++r) pmax = fmaxf(pmax, sc0[r]);
#pragma unroll
    for (int r = 0; r < 16; ++r) pmax = fmaxf(pmax, sc1[r]);
    pmax = fmaxf(pmax, __shfl_xor(pmax, 32));

    // defer-max (T13, THR=8 in log2 domain): rescale only when max grows
    if (__any(pmax > m + 8.0f)) {
      float mn = fmaxf(m, pmax);
      float sf = __builtin_amdgcn_exp2f(m - mn);
      m = mn;
      sflp[l31] = sf;                              // both halves write same value
      f32x4 s4[4];
#pragma unroll
      for (int g4 = 0; g4 < 4; ++g4) s4[g4] = *(const f32x4*)(sflp + g4 * 8 + hi * 4);
#pragma unroll
      for (int r = 0; r < 16; ++r) {
        float f = s4[r >> 2][r & 3];               // sf for O-row s=(r&3)+8(r>>2)+4hi
        O0[r] *= f; O1[r] *= f; lacc[r] *= f;
      }
    }

#pragma unroll
    for (int r = 0; r < 16; ++r) {
      sc0[r] = __builtin_amdgcn_exp2f(sc0[r] - m);
      sc1[r] = __builtin_amdgcn_exp2f(sc1[r] - m);
    }

    // P -> PV A-fragments in-register via shfl_xor(32).
    // Own chunk pairs: c0=(p0,p1) c1=(p2,p3) c2=(p4,p5) c3=(p6,p7), where
    // own p0..p3 = t {0..3}+4hi, p4..p7 = t {8..11}+4hi (within 16-t slice,
    // A-frag word w[j] must hold t = 8*hi + {2j, 2j+1}):
    //   hi=0 needs [c0, c1, partner.c0, partner.c1]  (t 0..7)
    //   hi=1 needs [partner.c2, partner.c3, c2, c3]  (t 8..15)
    uint4v paw[4];
    {
      auto mkchunk = [&](float p0, float p1, float p2, float p3,
                         float p4, float p5, float p6, float p7) -> uint4v {
        unsigned c0 = cvtpk(p0, p1), c1 = cvtpk(p2, p3);
        unsigned c2 = cvtpk(p4, p5), c3 = cvtpk(p6, p7);
        unsigned e0 = (unsigned)__shfl_xor((int)c0, 32);
        unsigned e1 = (unsigned)__shfl_xor((int)c1, 32);
        unsigned e2 = (unsigned)__shfl_xor((int)c2, 32);
        unsigned e3 = (unsigned)__shfl_xor((int)c3, 32);
        uint4v w;
        w[0] = hi ? e2 : c0;
        w[1] = hi ? e3 : c1;
        w[2] = hi ? c2 : e0;
        w[3] = hi ? c3 : e1;
        return w;
      };
      paw[0] = mkchunk(sc0[0], sc0[1], sc0[2], sc0[3], sc0[4], sc0[5], sc0[6], sc0[7]);
      paw[1] = mkchunk(sc0[8], sc0[9], sc0[10], sc0[11], sc0[12], sc0[13], sc0[14], sc0[15]);
      paw[2] = mkchunk(sc1[0], sc1[1], sc1[2], sc1[3], sc1[4], sc1[5], sc1[6], sc1[7]);
      paw[3] = mkchunk(sc1[8], sc1[9], sc1[10], sc1[11], sc1[12], sc1[13], sc1[14], sc1[15]);
    }

    // l via ones-MFMA (lands in O layout -> zero-shuffle normalize) + PV
#pragma unroll
    for (int ks = 0; ks < 4; ++ks) {
      bf16x8 pa = __builtin_bit_cast(bf16x8, paw[ks]);
      lacc = __builtin_amdgcn_mfma_f32_32x32x16_bf16(pa, onesb, lacc, 0, 0, 0);
      int sw = ((ks * 2 + hi) ^ (l31 & 7)) << 4;
      bf16x8 v0 = *(const bf16x8*)(vbuf + l31 * 128 + sw);
      O0 = __builtin_amdgcn_mfma_f32_32x32x16_bf16(pa, v0, O0, 0, 0, 0);
      bf16x8 v1 = *(const bf16x8*)(vbuf + (32 + l31) * 128 + sw);
      O1 = __builtin_amdgcn_mfma_f32_32x32x16_bf16(pa, v1, O1, 0, 0, 0);
    }

    asm volatile("s_waitcnt vmcnt(0)" ::: "memory");
    __syncthreads();
  }

  // epilogue: normalize (lacc already per-O-row), transpose via per-wave LDS
  float rn[16];
#pragma unroll
  for (int r = 0; r < 16; ++r) rn[r] = 1.0f / lacc[r];
  float* ep = (float*)(smem + wv * 4608);          // [32 d][36 f32] per wave
  const size_t outbase = (size_t)bh * 262144 + (size_t)(s0 + wv * 32);
#pragma unroll
  for (int dt = 0; dt < 2; ++dt) {
    const f32x16& O = dt ? O1 : O0;
#pragma unroll
    for (int g4 = 0; g4 < 4; ++g4) {
      f32x4 w;
      w[0] = O[4 * g4 + 0] * rn[4 * g4 + 0];
      w[1] = O[4 * g4 + 1] * rn[4 * g4 + 1];
      w[2] = O[4 * g4 + 2] * rn[4 * g4 + 2];
      w[3] = O[4 * g4 + 3] * rn[4 * g4 + 3];
      *(f32x4*)(ep + l31 * 36 + g4 * 8 + hi * 4) = w;   // [d=l31][s_local]
    }
#pragma unroll
    for (int j = 0; j < 4; ++j) {
      int idx2 = j * 64 + lane;
      int d = idx2 >> 3, s4c = idx2 & 7;
      f32x4 vv = *(const f32x4*)(ep + d * 36 + s4c * 4);
      *(f32x4*)(out + outbase + (size_t)(dt * 32 + d) * 4096 + s4c * 4) = vv;
    }
  }
}

// ---------------------------------------------------------------------------
extern "C" void kernel_launch(void* const* d_in, const int* in_sizes, int n_in,
                              void* d_out, int out_size, void* d_ws, size_t ws_size,
                              hipStream_t stream) {
  const float* x = (const float*)d_in[0];
  const float* wdw = (const float*)d_in[1];
  const float* wpw = (const float*)d_in[2];
  float* out = (float*)d_out;
  char* ws = (char*)d_ws;
  unsigned short* dwt = (unsigned short*)(ws + OFF_DW);
  unsigned short* wbf = (unsigned short*)(ws + OFF_WB);
  unsigned short* q = (unsigned short*)(ws + OFF_Q);
  unsigned short* k = (unsigned short*)(ws + OFF_K);
  unsigned short* v = (unsigned short*)(ws + OFF_V);

  k_wcvt<<<dim3(768), dim3(256), 0, stream>>>(wpw, wbf);
  k_dw<<<dim3(64, 4, 4), dim3(256), 0, stream>>>(x, wdw, dwt);
  k_pw<<<dim3(64, 12, 4), dim3(256), 0, stream>>>(dwt, wbf, q, k, v);
  k_attn<<<dim3(256), dim3(512), 0, stream>>>(q, k, v, out);
}